// Round 1
// baseline (476.465 us; speedup 1.0000x reference)
//
#include <hip/hip_runtime.h>

#define N 4096
#define F 512
#define FP 64
#define K 8
#define KFP 512          // K*FP
#define NEG_SLOPE 0.2f

// ---------------- prep: adjacency int32 -> bitmask (uint64 per 64 columns) ----------------
__global__ void adj_to_bits(const int* __restrict__ adj,
                            unsigned long long* __restrict__ adjb, int nwords) {
  int gid  = blockIdx.x * blockDim.x + threadIdx.x;
  int wid  = gid >> 6;                 // global wave id
  int lane = threadIdx.x & 63;
  int nwaves = (gridDim.x * blockDim.x) >> 6;
  for (int w = wid; w < nwords; w += nwaves) {
    int row = w >> 6, wcol = w & 63;
    int v = adj[row * N + wcol * 64 + lane];
    unsigned long long m = __ballot(v > 0);
    if (lane == 0) adjb[w] = m;
  }
}

// ---------------- kernel A: h_t[n][k*64+p] = X·W  (+ f1, f2 via wave reduction) ----------
#define TN 16
__global__ __launch_bounds__(512) void compute_h(
    const float* __restrict__ X, const float* __restrict__ W,
    const float* __restrict__ a, float* __restrict__ h_t,
    float* __restrict__ f1, float* __restrict__ f2) {
  __shared__ __align__(16) float XL[TN][36];   // pad 36: 144B rows keep float4 alignment
  const int t = threadIdx.x;        // 512 threads; thread owns output column c = t
  const int c = t;
  const int k = t >> 6;
  const int p = t & 63;
  const int n0 = blockIdx.x * TN;

  float acc[TN];
#pragma unroll
  for (int r = 0; r < TN; r++) acc[r] = 0.f;

  for (int f0 = 0; f0 < F; f0 += 32) {
    __syncthreads();
    XL[t >> 5][t & 31] = X[(n0 + (t >> 5)) * F + f0 + (t & 31)];
    __syncthreads();
#pragma unroll
    for (int fq = 0; fq < 8; fq++) {
      float wv[4];
#pragma unroll
      for (int ff = 0; ff < 4; ff++)
        wv[ff] = W[(k * F + f0 + fq * 4 + ff) * FP + p];
#pragma unroll
      for (int r = 0; r < TN; r++) {
        const float4 xv = *reinterpret_cast<const float4*>(&XL[r][fq * 4]);
        acc[r] = fmaf(xv.x, wv[0], acc[r]);
        acc[r] = fmaf(xv.y, wv[1], acc[r]);
        acc[r] = fmaf(xv.z, wv[2], acc[r]);
        acc[r] = fmaf(xv.w, wv[3], acc[r]);
      }
    }
  }

  const float asrc = a[k * 128 + p];        // a[k, p, 0]
  const float adst = a[k * 128 + 64 + p];   // a[k, 64+p, 0]
#pragma unroll
  for (int r = 0; r < TN; r++) {
    h_t[(n0 + r) * KFP + c] = acc[r];
    float v1 = acc[r] * asrc;
    float v2 = acc[r] * adst;
#pragma unroll
    for (int s = 1; s < 64; s <<= 1) {
      v1 += __shfl_xor(v1, s);
      v2 += __shfl_xor(v2, s);
    }
    if (p == 0) { f1[k * N + n0 + r] = v1; f2[k * N + n0 + r] = v2; }
  }
}

// ---------------- kernel C: masked-softmax attention aggregation -------------------------
// block = (64-row tile, head k). 512 threads = 8 waves.
// out[i][k*64+p] = sum_j adj(i,j) * exp(lrelu(f2_i + f1_j)) * h[k][j][p] / den_i
#define TI 64
#define JT 64
__global__ __launch_bounds__(512) void attention(
    const float* __restrict__ h_t, const float* __restrict__ f1,
    const float* __restrict__ f2, const unsigned long long* __restrict__ adjb,
    float* __restrict__ out) {
  __shared__ __align__(16) float WL[JT][TI];  // 16 KB, [j][i]
  __shared__ float FL[JT];
  __shared__ float DEN[8][TI];
  __shared__ float DENT[TI];

  const int t = threadIdx.x;     // 512
  const int k = blockIdx.x & 7;
  const int i0 = (blockIdx.x >> 3) * TI;
  const int iown = t & 63;       // row this thread computes w for (phase A)
  const int q = t >> 6;          // wave id, 0..7
  const int p = t & 63;          // column lane (phase B)
  const int rbase = q * 8;       // wave q accumulates rows rbase..rbase+7

  const float f2r = f2[k * N + i0 + iown];
  const float* __restrict__ f1k = f1 + k * N;
  const float* __restrict__ hk = h_t + k * 64;

  float acc[8];
#pragma unroll
  for (int r = 0; r < 8; r++) acc[r] = 0.f;
  float den = 0.f;

  for (int j0 = 0; j0 < N; j0 += JT) {
    __syncthreads();                       // WL/FL safe to overwrite
    if (t < JT) FL[t] = f1k[j0 + t];
    const unsigned long long aw = adjb[(i0 + iown) * 64 + (j0 >> 6)];
    __syncthreads();                       // FL visible
    // phase A: thread computes w for rows=iown, j = q*8 + m
#pragma unroll
    for (int m = 0; m < 8; m++) {
      const int j = q * 8 + m;
      float s = f2r + FL[j];
      s = fmaxf(s, NEG_SLOPE * s);         // leaky relu
      float w = __expf(s);
      if (!((aw >> j) & 1ULL)) w = 0.f;
      WL[j][iown] = w;
      den += w;
    }
    __syncthreads();                       // WL visible
    // phase B: wave q: rows rbase..rbase+7, lane p
#pragma unroll 4
    for (int j = 0; j < JT; j++) {
      const float hv = hk[(j0 + j) * KFP + p];
      const float4 w0 = *reinterpret_cast<const float4*>(&WL[j][rbase]);
      const float4 w1 = *reinterpret_cast<const float4*>(&WL[j][rbase + 4]);
      acc[0] = fmaf(w0.x, hv, acc[0]);
      acc[1] = fmaf(w0.y, hv, acc[1]);
      acc[2] = fmaf(w0.z, hv, acc[2]);
      acc[3] = fmaf(w0.w, hv, acc[3]);
      acc[4] = fmaf(w1.x, hv, acc[4]);
      acc[5] = fmaf(w1.y, hv, acc[5]);
      acc[6] = fmaf(w1.z, hv, acc[6]);
      acc[7] = fmaf(w1.w, hv, acc[7]);
    }
  }

  DEN[q][iown] = den;
  __syncthreads();
  if (t < TI) {
    float d = 0.f;
#pragma unroll
    for (int qq = 0; qq < 8; qq++) d += DEN[qq][t];
    DENT[t] = d;
  }
  __syncthreads();
#pragma unroll
  for (int r = 0; r < 8; r++) {
    const int i = rbase + r;
    out[(i0 + i) * KFP + k * 64 + p] = acc[r] / DENT[i];
  }
}

// ---------------- launch ----------------------------------------------------------------
extern "C" void kernel_launch(void* const* d_in, const int* in_sizes, int n_in,
                              void* d_out, int out_size, void* d_ws, size_t ws_size,
                              hipStream_t stream) {
  const float* X   = (const float*)d_in[0];             // (N, F)
  const int*   adj = (const int*)d_in[1];               // (N, N)
  const float* W   = (const float*)d_in[2];             // (K, F, FP)
  const float* a   = (const float*)d_in[3];             // (K, 2*FP, 1)
  float* out = (float*)d_out;                           // (N, K*FP)

  char* ws = (char*)d_ws;
  float* h_t = (float*)(ws);                            // 8 MB
  float* f1  = (float*)(ws + 8388608);                  // 128 KB
  float* f2  = (float*)(ws + 8519680);                  // 128 KB
  unsigned long long* adjb = (unsigned long long*)(ws + 8650752);  // 2 MB

  const int nwords = N * (N / 64);
  hipLaunchKernelGGL(adj_to_bits, dim3(1024), dim3(256), 0, stream, adj, adjb, nwords);
  hipLaunchKernelGGL(compute_h, dim3(N / TN), dim3(512), 0, stream, X, W, a, h_t, f1, f2);
  hipLaunchKernelGGL(attention, dim3((N / TI) * K), dim3(512), 0, stream, h_t, f1, f2, adjb, out);
}

// Round 2
// 276.823 us; speedup vs baseline: 1.7212x; 1.7212x over previous
//
#include <hip/hip_runtime.h>

#define N 4096
#define F 512
#define FP 64
#define K 8
#define KFP 512          // K*FP
#define NEG_SLOPE 0.2f

typedef __attribute__((ext_vector_type(8))) short short8;
typedef __attribute__((ext_vector_type(4))) float f32x4;

__device__ __forceinline__ unsigned short f2bs(float x) {
  union { __bf16 b; unsigned short u; } u;
  u.b = (__bf16)x;
  return u.u;
}

// ---------------- prep: adjacency int32 -> bitmask (uint64 per 64 columns) ----------------
__global__ void adj_to_bits(const int* __restrict__ adj,
                            unsigned long long* __restrict__ adjb, int nwords) {
  int gid  = blockIdx.x * blockDim.x + threadIdx.x;
  int wid  = gid >> 6;                 // global wave id
  int lane = threadIdx.x & 63;
  int nwaves = (gridDim.x * blockDim.x) >> 6;
  for (int w = wid; w < nwords; w += nwaves) {
    int row = w >> 6, wcol = w & 63;
    int v = adj[row * N + wcol * 64 + lane];
    unsigned long long m = __ballot(v > 0);
    if (lane == 0) adjb[w] = m;
  }
}

// ---------------- kernel A: h_bT[k*64+p][n] = bf16(X·W)  (+ f1, f2) ----------------------
#define TN 16
__global__ __launch_bounds__(512) void compute_h(
    const float* __restrict__ X, const float* __restrict__ W,
    const float* __restrict__ a, unsigned short* __restrict__ h_bT,
    float* __restrict__ f1, float* __restrict__ f2) {
  __shared__ __align__(16) float XL[TN][36];
  const int t = threadIdx.x;        // 512 threads; thread owns output column c = t
  const int c = t;
  const int k = t >> 6;
  const int p = t & 63;
  const int n0 = blockIdx.x * TN;

  float acc[TN];
#pragma unroll
  for (int r = 0; r < TN; r++) acc[r] = 0.f;

  for (int f0 = 0; f0 < F; f0 += 32) {
    __syncthreads();
    XL[t >> 5][t & 31] = X[(n0 + (t >> 5)) * F + f0 + (t & 31)];
    __syncthreads();
#pragma unroll
    for (int fq = 0; fq < 8; fq++) {
      float wv[4];
#pragma unroll
      for (int ff = 0; ff < 4; ff++)
        wv[ff] = W[(k * F + f0 + fq * 4 + ff) * FP + p];
#pragma unroll
      for (int r = 0; r < TN; r++) {
        const float4 xv = *reinterpret_cast<const float4*>(&XL[r][fq * 4]);
        acc[r] = fmaf(xv.x, wv[0], acc[r]);
        acc[r] = fmaf(xv.y, wv[1], acc[r]);
        acc[r] = fmaf(xv.z, wv[2], acc[r]);
        acc[r] = fmaf(xv.w, wv[3], acc[r]);
      }
    }
  }

  // bf16 transposed store: h_bT[(k*64+p)][n0..n0+15]
  unsigned short hs[16];
#pragma unroll
  for (int r = 0; r < TN; r++) hs[r] = f2bs(acc[r]);
  *reinterpret_cast<uint4*>(&h_bT[(size_t)c * N + n0])     = *reinterpret_cast<uint4*>(&hs[0]);
  *reinterpret_cast<uint4*>(&h_bT[(size_t)c * N + n0 + 8]) = *reinterpret_cast<uint4*>(&hs[8]);

  const float asrc = a[k * 128 + p];        // a[k, p, 0]
  const float adst = a[k * 128 + 64 + p];   // a[k, 64+p, 0]
#pragma unroll
  for (int r = 0; r < TN; r++) {
    float v1 = acc[r] * asrc;
    float v2 = acc[r] * adst;
#pragma unroll
    for (int s = 1; s < 64; s <<= 1) {
      v1 += __shfl_xor(v1, s);
      v2 += __shfl_xor(v2, s);
    }
    if (p == 0) { f1[k * N + n0 + r] = v1; f2[k * N + n0 + r] = v2; }
  }
}

// ---------------- kernel C: MFMA masked-softmax attention aggregation --------------------
// block = (64-row i-tile, head k), 512 threads = 8 waves = 4 i-strips x 2 j-halves.
// Wave (wq,jq): A-frag = exp-scores for rows i0+wq*16..+15, its j-half; B = h_bT.
__global__ __launch_bounds__(512) void attn_mfma(
    const unsigned short* __restrict__ h_bT, const float* __restrict__ f1,
    const float* __restrict__ f2, const unsigned long long* __restrict__ adjb,
    float* __restrict__ out) {
  __shared__ float CL[4][16][64];   // 16 KB partial-C exchange
  __shared__ float DL[4][2][16];    // denominators

  const int t = threadIdx.x;
  const int k = blockIdx.x & 7;
  const int i0 = (blockIdx.x >> 3) * 64;
  const int wave = t >> 6, lane = t & 63;
  const int wq = wave >> 1, jq = wave & 1;
  const int col = lane & 15, kg = lane >> 4;    // A row (m) / k-group
  const int rowi = i0 + wq * 16 + col;

  const float f2r = f2[k * N + rowi];
  const float* __restrict__ f1k = f1 + k * N;
  const unsigned short* __restrict__ hb = h_bT + (size_t)k * 64 * N;
  const unsigned long long* __restrict__ arow = adjb + (size_t)rowi * 64;

  f32x4 acc[4];
#pragma unroll
  for (int n = 0; n < 4; n++) acc[n] = (f32x4){0.f, 0.f, 0.f, 0.f};
  float den = 0.f;

  for (int j0 = jq * 32; j0 < N; j0 += 64) {
    // B fragments: lane reads 8 consecutive bf16 along j (16B load)
    short8 bfrag[4];
#pragma unroll
    for (int n = 0; n < 4; n++)
      bfrag[n] = *reinterpret_cast<const short8*>(
          &hb[(size_t)(n * 16 + col) * N + j0 + kg * 8]);

    const float4 fa = *reinterpret_cast<const float4*>(&f1k[j0 + kg * 8]);
    const float4 fb = *reinterpret_cast<const float4*>(&f1k[j0 + kg * 8 + 4]);
    const unsigned long long aw = arow[j0 >> 6];
    const unsigned mb = (unsigned)(aw >> ((j0 & 32) + kg * 8)) & 0xffu;

    const float fv[8] = {fa.x, fa.y, fa.z, fa.w, fb.x, fb.y, fb.z, fb.w};
    short8 afrag;
#pragma unroll
    for (int e = 0; e < 8; e++) {
      float s = f2r + fv[e];
      s = fmaxf(s, NEG_SLOPE * s);           // leaky relu
      float w = __expf(s);
      w = (mb & (1u << e)) ? w : 0.f;        // adjacency mask
      den += w;
      afrag[e] = (short)f2bs(w);
    }

#pragma unroll
    for (int n = 0; n < 4; n++)
      acc[n] = __builtin_amdgcn_mfma_f32_16x16x32_bf16(afrag, bfrag[n], acc[n], 0, 0, 0);
  }

  // denominator: reduce across k-groups (lanes sharing lane&15)
  den += __shfl_xor(den, 16);
  den += __shfl_xor(den, 32);
  if (lane < 16) DL[wq][jq][lane] = den;
  if (jq == 1) {
#pragma unroll
    for (int n = 0; n < 4; n++)
#pragma unroll
      for (int r = 0; r < 4; r++)
        CL[wq][kg * 4 + r][n * 16 + col] = acc[n][r];
  }
  __syncthreads();
  if (jq == 0) {
    float rinv[4];
#pragma unroll
    for (int r = 0; r < 4; r++)
      rinv[r] = 1.f / (DL[wq][0][kg * 4 + r] + DL[wq][1][kg * 4 + r]);
#pragma unroll
    for (int n = 0; n < 4; n++)
#pragma unroll
      for (int r = 0; r < 4; r++) {
        const float v = (acc[n][r] + CL[wq][kg * 4 + r][n * 16 + col]) * rinv[r];
        out[(size_t)(i0 + wq * 16 + kg * 4 + r) * KFP + k * 64 + n * 16 + col] = v;
      }
  }
}

// ---------------- launch ----------------------------------------------------------------
extern "C" void kernel_launch(void* const* d_in, const int* in_sizes, int n_in,
                              void* d_out, int out_size, void* d_ws, size_t ws_size,
                              hipStream_t stream) {
  const float* X   = (const float*)d_in[0];             // (N, F)
  const int*   adj = (const int*)d_in[1];               // (N, N)
  const float* W   = (const float*)d_in[2];             // (K, F, FP)
  const float* a   = (const float*)d_in[3];             // (K, 2*FP, 1)
  float* out = (float*)d_out;                           // (N, K*FP)

  char* ws = (char*)d_ws;
  unsigned short* h_bT = (unsigned short*)(ws);                    // 4 MB  (K*FP x N bf16)
  float* f1  = (float*)(ws + 4194304);                             // 128 KB
  float* f2  = (float*)(ws + 4325376);                             // 128 KB
  unsigned long long* adjb = (unsigned long long*)(ws + 4456448);  // 2 MB

  const int nwords = N * (N / 64);
  hipLaunchKernelGGL(adj_to_bits, dim3(1024), dim3(256), 0, stream, adj, adjb, nwords);
  hipLaunchKernelGGL(compute_h, dim3(N / TN), dim3(512), 0, stream, X, W, a, h_bT, f1, f2);
  hipLaunchKernelGGL(attn_mfma, dim3((N / 64) * K), dim3(512), 0, stream,
                     h_bT, f1, f2, adjb, out);
}

// Round 3
// 182.030 us; speedup vs baseline: 2.6175x; 1.5208x over previous
//
#include <hip/hip_runtime.h>

#define N 4096
#define F 512
#define FP 64
#define K 8
#define KFP 512          // K*FP
#define NEG_SLOPE 0.2f

#define BI 64            // i-rows per block
#define BJ 256           // j-cols staged per tile
#define NTILE (N / BJ)   // 16

typedef __attribute__((ext_vector_type(8))) short short8;
typedef __attribute__((ext_vector_type(4))) float f32x4;

__device__ __forceinline__ unsigned short f2bs(float x) {
  union { __bf16 b; unsigned short u; } u;
  u.b = (__bf16)x;
  return u.u;
}

// ---------------- prep: adjacency int32 -> bitmask (uint64 per 64 columns) ----------------
__global__ void adj_to_bits(const int* __restrict__ adj,
                            unsigned long long* __restrict__ adjb, int nwords) {
  int gid  = blockIdx.x * blockDim.x + threadIdx.x;
  int wid  = gid >> 6;
  int lane = threadIdx.x & 63;
  int nwaves = (gridDim.x * blockDim.x) >> 6;
  for (int w = wid; w < nwords; w += nwaves) {
    int row = w >> 6, wcol = w & 63;
    int v = adj[row * N + wcol * 64 + lane];
    unsigned long long m = __ballot(v > 0);
    if (lane == 0) adjb[w] = m;
  }
}

// ---------------- kernel A: h_bT[k*64+p][n] = bf16(X·W)  (+ f1, f2) ----------------------
#define TN 16
__global__ __launch_bounds__(512) void compute_h(
    const float* __restrict__ X, const float* __restrict__ W,
    const float* __restrict__ a, unsigned short* __restrict__ h_bT,
    float* __restrict__ f1, float* __restrict__ f2) {
  __shared__ __align__(16) float XL[TN][36];
  const int t = threadIdx.x;
  const int c = t;
  const int k = t >> 6;
  const int p = t & 63;
  const int n0 = blockIdx.x * TN;

  float acc[TN];
#pragma unroll
  for (int r = 0; r < TN; r++) acc[r] = 0.f;

  for (int f0 = 0; f0 < F; f0 += 32) {
    __syncthreads();
    XL[t >> 5][t & 31] = X[(n0 + (t >> 5)) * F + f0 + (t & 31)];
    __syncthreads();
#pragma unroll
    for (int fq = 0; fq < 8; fq++) {
      float wv[4];
#pragma unroll
      for (int ff = 0; ff < 4; ff++)
        wv[ff] = W[(k * F + f0 + fq * 4 + ff) * FP + p];
#pragma unroll
      for (int r = 0; r < TN; r++) {
        const float4 xv = *reinterpret_cast<const float4*>(&XL[r][fq * 4]);
        acc[r] = fmaf(xv.x, wv[0], acc[r]);
        acc[r] = fmaf(xv.y, wv[1], acc[r]);
        acc[r] = fmaf(xv.z, wv[2], acc[r]);
        acc[r] = fmaf(xv.w, wv[3], acc[r]);
      }
    }
  }

  unsigned short hs[16];
#pragma unroll
  for (int r = 0; r < TN; r++) hs[r] = f2bs(acc[r]);
  *reinterpret_cast<uint4*>(&h_bT[(size_t)c * N + n0])     = *reinterpret_cast<uint4*>(&hs[0]);
  *reinterpret_cast<uint4*>(&h_bT[(size_t)c * N + n0 + 8]) = *reinterpret_cast<uint4*>(&hs[8]);

  const float asrc = a[k * 128 + p];
  const float adst = a[k * 128 + 64 + p];
#pragma unroll
  for (int r = 0; r < TN; r++) {
    float v1 = acc[r] * asrc;
    float v2 = acc[r] * adst;
#pragma unroll
    for (int s = 1; s < 64; s <<= 1) {
      v1 += __shfl_xor(v1, s);
      v2 += __shfl_xor(v2, s);
    }
    if (p == 0) { f1[k * N + n0 + r] = v1; f2[k * N + n0 + r] = v2; }
  }
}

// ---------------- kernel C: LDS-staged MFMA masked-softmax attention ---------------------
// block = (64 i-rows, head k). 8 waves = 2 i-groups x 4 j-quarters.
// LDS: HL[2][64 p][256 j] bf16, XOR-swizzled 16B units (phys_u = u ^ (row&15)).
__global__ __launch_bounds__(512, 4) void attn_mfma(
    const unsigned short* __restrict__ h_bT, const float* __restrict__ f1,
    const float* __restrict__ f2, const unsigned long long* __restrict__ adjb,
    float* __restrict__ out) {
  __shared__ __align__(16) unsigned char SMEM[65536];   // HL dbuf; aliased as CL at end
  __shared__ float DL[2][4][32];

  const int tid = threadIdx.x;
  const int k = blockIdx.x & 7;
  const int i0 = (blockIdx.x >> 3) * BI;
  const int wave = tid >> 6, lane = tid & 63;
  const int iq = wave >> 2;          // 0..1 : i-group of 32 rows
  const int jq = wave & 3;           // 0..3 : j-quarter of 64 cols
  const int col = lane & 15, kg = lane >> 4;

  const float* __restrict__ f1k = f1 + k * N;
  const unsigned char* __restrict__ hbb =
      (const unsigned char*)(h_bT + (size_t)k * 64 * N);

  const int rbase = i0 + iq * 32;
  const float f2r0 = f2[k * N + rbase + col];
  const float f2r1 = f2[k * N + rbase + 16 + col];
  const unsigned long long* __restrict__ arow0 = adjb + (size_t)(rbase + col) * 64;
  const unsigned long long* __restrict__ arow1 = adjb + (size_t)(rbase + 16 + col) * 64;

  f32x4 acc[2][4];
  f32x4 accden[2];
#pragma unroll
  for (int a = 0; a < 2; a++) {
    accden[a] = (f32x4){0.f, 0.f, 0.f, 0.f};
#pragma unroll
    for (int n = 0; n < 4; n++) acc[a][n] = (f32x4){0.f, 0.f, 0.f, 0.f};
  }
  short8 bones;
#pragma unroll
  for (int e = 0; e < 8; e++) bones[e] = (short)0x3F80;

  // ---- staging: 32KB tile, 4 global_load_lds x16B per wave, pre-swizzled source ----
  auto stage = [&](int tt, int buf) {
#pragma unroll
    for (int m = 0; m < 4; m++) {
      const int g = wave * 4 + m;                 // 0..31
      const int row = g * 2 + (lane >> 5);        // 0..63 (p)
      const int pu = lane & 31;                   // physical 16B slot
      const int u = pu ^ (row & 15);              // logical j-chunk
      const void* src = hbb + (size_t)row * (N * 2) + tt * (BJ * 2) + u * 16;
      void* dst = (void*)(SMEM + buf * 32768 + g * 1024);  // wave-uniform base
      __builtin_amdgcn_global_load_lds(
          (const __attribute__((address_space(1))) void*)src,
          (__attribute__((address_space(3))) void*)dst, 16, 0, 0);
    }
  };

  auto compute_tile = [&](int tt, int buf) {
    const unsigned long long aw0 = arow0[tt * 4 + jq];
    const unsigned long long aw1 = arow1[tt * 4 + jq];
#pragma unroll
    for (int ks = 0; ks < 2; ks++) {
      const int jglob = tt * BJ + jq * 64 + ks * 32;
      const float4 fa = *reinterpret_cast<const float4*>(&f1k[jglob + kg * 8]);
      const float4 fb = *reinterpret_cast<const float4*>(&f1k[jglob + kg * 8 + 4]);

      short8 bfrag[4];
#pragma unroll
      for (int n = 0; n < 4; n++) {
        const int row_b = n * 16 + col;
        const int u = jq * 8 + ks * 4 + kg;
        const int pu = u ^ col;                  // row_b & 15 == col
        bfrag[n] = *reinterpret_cast<const short8*>(
            SMEM + buf * 32768 + row_b * 512 + pu * 16);
      }

      const unsigned mb0 = (unsigned)(aw0 >> (ks * 32 + kg * 8)) & 0xffu;
      const unsigned mb1 = (unsigned)(aw1 >> (ks * 32 + kg * 8)) & 0xffu;
      const float fv[8] = {fa.x, fa.y, fa.z, fa.w, fb.x, fb.y, fb.z, fb.w};
      short8 af0, af1;
#pragma unroll
      for (int e = 0; e < 8; e++) {
        float s0 = f2r0 + fv[e];
        s0 = fmaxf(s0, NEG_SLOPE * s0);
        float w0 = __expf(s0);
        w0 = (mb0 & (1u << e)) ? w0 : 0.f;
        af0[e] = (short)f2bs(w0);
        float s1 = f2r1 + fv[e];
        s1 = fmaxf(s1, NEG_SLOPE * s1);
        float w1 = __expf(s1);
        w1 = (mb1 & (1u << e)) ? w1 : 0.f;
        af1[e] = (short)f2bs(w1);
      }

      accden[0] = __builtin_amdgcn_mfma_f32_16x16x32_bf16(af0, bones, accden[0], 0, 0, 0);
      accden[1] = __builtin_amdgcn_mfma_f32_16x16x32_bf16(af1, bones, accden[1], 0, 0, 0);
#pragma unroll
      for (int n = 0; n < 4; n++) {
        acc[0][n] = __builtin_amdgcn_mfma_f32_16x16x32_bf16(af0, bfrag[n], acc[0][n], 0, 0, 0);
        acc[1][n] = __builtin_amdgcn_mfma_f32_16x16x32_bf16(af1, bfrag[n], acc[1][n], 0, 0, 0);
      }
    }
  };

  // ---- pipelined main loop: 1-deep prefetch, counted vmcnt ----
  stage(0, 0);
  for (int t = 0; t < NTILE; ++t) {
    const int cur = t & 1;
    __builtin_amdgcn_s_barrier();            // A: all readers of buf[1-cur] done
    __builtin_amdgcn_sched_barrier(0);
    if (t + 1 < NTILE) {
      stage(t + 1, 1 - cur);
      asm volatile("s_waitcnt vmcnt(4)" ::: "memory");   // wait stage(t), keep stage(t+1)
    } else {
      asm volatile("s_waitcnt vmcnt(0)" ::: "memory");
    }
    __builtin_amdgcn_s_barrier();            // B: buf[cur] staged for all waves
    __builtin_amdgcn_sched_barrier(0);
    compute_tile(t, cur);
  }
  __syncthreads();

  // ---- cross-jq reduction (CL aliases HL) + normalize + store ----
  float* CL = (float*)SMEM;                  // [iq][jqsrc-1][32][64] = 48KB
  if (jq != 0) {
#pragma unroll
    for (int a = 0; a < 2; a++) {
#pragma unroll
      for (int n = 0; n < 4; n++)
#pragma unroll
        for (int r = 0; r < 4; r++)
          CL[((iq * 3 + (jq - 1)) * 32 + a * 16 + kg * 4 + r) * 64 + n * 16 + col] =
              acc[a][n][r];
      if (col == 0)
#pragma unroll
        for (int r = 0; r < 4; r++) DL[iq][jq][a * 16 + kg * 4 + r] = accden[a][r];
    }
  } else {
#pragma unroll
    for (int a = 0; a < 2; a++)
      if (col == 0)
#pragma unroll
        for (int r = 0; r < 4; r++) DL[iq][0][a * 16 + kg * 4 + r] = accden[a][r];
  }
  __syncthreads();
  if (jq == 0) {
#pragma unroll
    for (int a = 0; a < 2; a++) {
#pragma unroll
      for (int r = 0; r < 4; r++) {
        const int il = a * 16 + kg * 4 + r;
        const float den = DL[iq][0][il] + DL[iq][1][il] + DL[iq][2][il] + DL[iq][3][il];
        const float rinv = 1.f / den;
#pragma unroll
        for (int n = 0; n < 4; n++) {
          float v = acc[a][n][r];
          v += CL[((iq * 3 + 0) * 32 + il) * 64 + n * 16 + col];
          v += CL[((iq * 3 + 1) * 32 + il) * 64 + n * 16 + col];
          v += CL[((iq * 3 + 2) * 32 + il) * 64 + n * 16 + col];
          out[(size_t)(i0 + iq * 32 + il) * KFP + k * 64 + n * 16 + col] = v * rinv;
        }
      }
    }
  }
}

// ---------------- launch ----------------------------------------------------------------
extern "C" void kernel_launch(void* const* d_in, const int* in_sizes, int n_in,
                              void* d_out, int out_size, void* d_ws, size_t ws_size,
                              hipStream_t stream) {
  const float* X   = (const float*)d_in[0];             // (N, F)
  const int*   adj = (const int*)d_in[1];               // (N, N)
  const float* W   = (const float*)d_in[2];             // (K, F, FP)
  const float* a   = (const float*)d_in[3];             // (K, 2*FP, 1)
  float* out = (float*)d_out;                           // (N, K*FP)

  char* ws = (char*)d_ws;
  unsigned short* h_bT = (unsigned short*)(ws);                    // 4 MB  (K*FP x N bf16)
  float* f1  = (float*)(ws + 4194304);                             // 128 KB
  float* f2  = (float*)(ws + 4325376);                             // 128 KB
  unsigned long long* adjb = (unsigned long long*)(ws + 4456448);  // 2 MB

  const int nwords = N * (N / 64);
  hipLaunchKernelGGL(adj_to_bits, dim3(1024), dim3(256), 0, stream, adj, adjb, nwords);
  hipLaunchKernelGGL(compute_h, dim3(N / TN), dim3(512), 0, stream, X, W, a, h_bT, f1, f2);
  hipLaunchKernelGGL(attn_mfma, dim3((N / BI) * K), dim3(512), 0, stream,
                     h_bT, f1, f2, adjb, out);
}

// Round 4
// 106.712 us; speedup vs baseline: 4.4650x; 1.7058x over previous
//
#include <hip/hip_runtime.h>

#define N 4096
#define F 512
#define FP 64
#define K 8
#define KFP 512          // K*FP
#define NEG_SLOPE 0.2f

#define BI 64            // attn: i-rows per block
#define BJ 256           // attn: j-cols staged per tile
#define NTILE (N / BJ)   // 16

typedef __attribute__((ext_vector_type(8))) short short8;
typedef __attribute__((ext_vector_type(4))) float f32x4;

__device__ __forceinline__ unsigned short f2bs(float x) {
  union { __bf16 b; unsigned short u; } u;
  u.b = (__bf16)x;
  return u.u;
}

// ---------------- prep: adjacency int32 -> bitmask ---------------------------------------
__global__ void adj_to_bits(const int* __restrict__ adj,
                            unsigned long long* __restrict__ adjb, int nwords) {
  int gid  = blockIdx.x * blockDim.x + threadIdx.x;
  int wid  = gid >> 6;
  int lane = threadIdx.x & 63;
  int nwaves = (gridDim.x * blockDim.x) >> 6;
  for (int w = wid; w < nwords; w += nwaves) {
    int row = w >> 6, wcol = w & 63;
    int v = adj[row * N + wcol * 64 + lane];
    unsigned long long m = __ballot(v > 0);
    if (lane == 0) adjb[w] = m;
  }
}

// ---------------- prep: X fp32 -> bf16 (row-major [N][F]) --------------------------------
__global__ __launch_bounds__(256) void xb_prep(const float* __restrict__ X,
                                               unsigned short* __restrict__ Xb) {
  const int idx = (blockIdx.x * 256 + threadIdx.x) * 8;   // grid sized exactly
  const float4 v0 = *reinterpret_cast<const float4*>(&X[idx]);
  const float4 v1 = *reinterpret_cast<const float4*>(&X[idx + 4]);
  unsigned short o[8] = {f2bs(v0.x), f2bs(v0.y), f2bs(v0.z), f2bs(v0.w),
                         f2bs(v1.x), f2bs(v1.y), f2bs(v1.z), f2bs(v1.w)};
  *reinterpret_cast<uint4*>(&Xb[idx]) = *reinterpret_cast<uint4*>(&o[0]);
}

// ---------------- prep: W [K][F][FP] fp32 -> Wt [K*FP][F] bf16 ---------------------------
__global__ __launch_bounds__(256) void wt_prep(const float* __restrict__ W,
                                               unsigned short* __restrict__ Wt) {
  __shared__ unsigned short WT16[64][66];   // pad 66: stride 33 dwords -> conflict-free
  const int t = threadIdx.x;
  const int k = blockIdx.x >> 3;
  const int f0 = (blockIdx.x & 7) * 64;
#pragma unroll
  for (int j = 0; j < 16; j++) {
    const int idx = j * 256 + t;            // 0..4095
    const int fl = idx >> 6, p = idx & 63;
    WT16[p][fl] = f2bs(W[(k * F + f0 + fl) * FP + p]);
  }
  __syncthreads();
  const int p = t >> 2, uc = t & 3;
  unsigned short tmp[16];
#pragma unroll
  for (int j = 0; j < 16; j++) tmp[j] = WT16[p][uc * 16 + j];
  unsigned short* dst = &Wt[(k * 64 + p) * F + f0 + uc * 16];
  *reinterpret_cast<uint4*>(dst)     = *reinterpret_cast<uint4*>(&tmp[0]);
  *reinterpret_cast<uint4*>(dst + 8) = *reinterpret_cast<uint4*>(&tmp[8]);
}

// ---------------- kernel A: h_bT = Wt·Xb^T via MFMA, fused f1/f2 -------------------------
// block = (head k, 64-node tile). 4 waves = 2 c-groups x 2 n-groups, wave = 32c x 32n.
__global__ __launch_bounds__(256, 2) void gemm_h(
    const unsigned short* __restrict__ Xb, const unsigned short* __restrict__ Wt,
    const float* __restrict__ a, unsigned short* __restrict__ h_bT,
    float* __restrict__ f1, float* __restrict__ f2) {
  __shared__ __align__(16) unsigned char AT[2][8192];   // Wt tile [64c][8u][16B]
  __shared__ __align__(16) unsigned char BT[2][8192];   // Xb tile [64n][8u][16B]
  __shared__ float F1L[2][64], F2L[2][64];

  const int t = threadIdx.x;
  const int k = blockIdx.x & 7;
  const int n0 = (blockIdx.x >> 3) * 64;
  const int wave = t >> 6, lane = t & 63;
  const int cg = wave >> 1, ng = wave & 1;
  const int col = lane & 15, kg = lane >> 4;
  const unsigned short* __restrict__ Wk = Wt + (size_t)k * 64 * F;

  f32x4 acc[2][2];
#pragma unroll
  for (int i = 0; i < 2; i++)
#pragma unroll
    for (int j = 0; j < 2; j++) acc[i][j] = (f32x4){0.f, 0.f, 0.f, 0.f};

  auto stage = [&](int tt, int buf) {
    const int f0 = tt * 64;
#pragma unroll
    for (int m = 0; m < 2; m++) {
      const int g = wave * 128 + m * 64 + lane;      // unit 0..511
      const int row = g >> 3, pu = g & 7;
      const int u = pu ^ (row & 7);                  // pre-swizzled source
      const void* srcA = Wk + (size_t)row * F + f0 + u * 8;
      void* dstA = (void*)(AT[buf] + (wave * 128 + m * 64) * 16);
      __builtin_amdgcn_global_load_lds(
          (const __attribute__((address_space(1))) void*)srcA,
          (__attribute__((address_space(3))) void*)dstA, 16, 0, 0);
      const void* srcB = Xb + (size_t)(n0 + row) * F + f0 + u * 8;
      void* dstB = (void*)(BT[buf] + (wave * 128 + m * 64) * 16);
      __builtin_amdgcn_global_load_lds(
          (const __attribute__((address_space(1))) void*)srcB,
          (__attribute__((address_space(3))) void*)dstB, 16, 0, 0);
    }
  };

  auto compute = [&](int buf) {
#pragma unroll
    for (int ks = 0; ks < 2; ks++) {
      const int u0 = ks * 4 + kg;
      short8 af[2], bf[2];
#pragma unroll
      for (int i = 0; i < 2; i++) {
        const int rowA = cg * 32 + i * 16 + col;
        af[i] = *reinterpret_cast<const short8*>(
            AT[buf] + (rowA * 8 + (u0 ^ (rowA & 7))) * 16);
        const int rowB = ng * 32 + i * 16 + col;
        bf[i] = *reinterpret_cast<const short8*>(
            BT[buf] + (rowB * 8 + (u0 ^ (rowB & 7))) * 16);
      }
#pragma unroll
      for (int i = 0; i < 2; i++)
#pragma unroll
        for (int j = 0; j < 2; j++)
          acc[i][j] = __builtin_amdgcn_mfma_f32_16x16x32_bf16(af[i], bf[j], acc[i][j], 0, 0, 0);
    }
  };

  stage(0, 0);
  for (int tt = 0; tt < F / 64; ++tt) {
    const int cur = tt & 1;
    __builtin_amdgcn_s_barrier();
    __builtin_amdgcn_sched_barrier(0);
    if (tt + 1 < F / 64) {
      stage(tt + 1, 1 - cur);
      asm volatile("s_waitcnt vmcnt(4)" ::: "memory");
    } else {
      asm volatile("s_waitcnt vmcnt(0)" ::: "memory");
    }
    __builtin_amdgcn_s_barrier();
    __builtin_amdgcn_sched_barrier(0);
    compute(cur);
  }

  // ---- epilogue: h_bT bf16 stores + fused f1/f2 from fp32 acc ----
  float p1[2] = {0.f, 0.f}, p2[2] = {0.f, 0.f};
#pragma unroll
  for (int i = 0; i < 2; i++) {
#pragma unroll
    for (int r = 0; r < 4; r++) {
      const int p = cg * 32 + i * 16 + kg * 4 + r;
      const float as = a[k * 128 + p];
      const float ad = a[k * 128 + 64 + p];
#pragma unroll
      for (int j = 0; j < 2; j++) {
        const float v = acc[i][j][r];
        h_bT[(size_t)(k * 64 + p) * N + n0 + ng * 32 + j * 16 + col] = f2bs(v);
        p1[j] = fmaf(v, as, p1[j]);
        p2[j] = fmaf(v, ad, p2[j]);
      }
    }
  }
#pragma unroll
  for (int j = 0; j < 2; j++) {
    p1[j] += __shfl_xor(p1[j], 16); p1[j] += __shfl_xor(p1[j], 32);
    p2[j] += __shfl_xor(p2[j], 16); p2[j] += __shfl_xor(p2[j], 32);
    if (kg == 0) {
      F1L[cg][ng * 32 + j * 16 + col] = p1[j];
      F2L[cg][ng * 32 + j * 16 + col] = p2[j];
    }
  }
  __syncthreads();
  if (t < 64) {
    f1[k * N + n0 + t] = F1L[0][t] + F1L[1][t];
    f2[k * N + n0 + t] = F2L[0][t] + F2L[1][t];
  }
}

// ---------------- kernel C: LDS-staged MFMA masked-softmax attention ---------------------
__global__ __launch_bounds__(512, 4) void attn_mfma(
    const unsigned short* __restrict__ h_bT, const float* __restrict__ f1,
    const float* __restrict__ f2, const unsigned long long* __restrict__ adjb,
    float* __restrict__ out) {
  __shared__ __align__(16) unsigned char SMEM[65536];
  __shared__ float DL[2][4][32];

  const int tid = threadIdx.x;
  const int k = blockIdx.x & 7;
  const int i0 = (blockIdx.x >> 3) * BI;
  const int wave = tid >> 6, lane = tid & 63;
  const int iq = wave >> 2;
  const int jq = wave & 3;
  const int col = lane & 15, kg = lane >> 4;

  const float* __restrict__ f1k = f1 + k * N;
  const unsigned char* __restrict__ hbb =
      (const unsigned char*)(h_bT + (size_t)k * 64 * N);

  const int rbase = i0 + iq * 32;
  const float f2r0 = f2[k * N + rbase + col];
  const float f2r1 = f2[k * N + rbase + 16 + col];
  const unsigned long long* __restrict__ arow0 = adjb + (size_t)(rbase + col) * 64;
  const unsigned long long* __restrict__ arow1 = adjb + (size_t)(rbase + 16 + col) * 64;

  f32x4 acc[2][4];
  f32x4 accden[2];
#pragma unroll
  for (int a = 0; a < 2; a++) {
    accden[a] = (f32x4){0.f, 0.f, 0.f, 0.f};
#pragma unroll
    for (int n = 0; n < 4; n++) acc[a][n] = (f32x4){0.f, 0.f, 0.f, 0.f};
  }
  short8 bones;
#pragma unroll
  for (int e = 0; e < 8; e++) bones[e] = (short)0x3F80;

  auto stage = [&](int tt, int buf) {
#pragma unroll
    for (int m = 0; m < 4; m++) {
      const int g = wave * 4 + m;
      const int row = g * 2 + (lane >> 5);
      const int pu = lane & 31;
      const int u = pu ^ (row & 15);
      const void* src = hbb + (size_t)row * (N * 2) + tt * (BJ * 2) + u * 16;
      void* dst = (void*)(SMEM + buf * 32768 + g * 1024);
      __builtin_amdgcn_global_load_lds(
          (const __attribute__((address_space(1))) void*)src,
          (__attribute__((address_space(3))) void*)dst, 16, 0, 0);
    }
  };

  auto compute_tile = [&](int tt, int buf) {
    const unsigned long long aw0 = arow0[tt * 4 + jq];
    const unsigned long long aw1 = arow1[tt * 4 + jq];
#pragma unroll
    for (int ks = 0; ks < 2; ks++) {
      const int jglob = tt * BJ + jq * 64 + ks * 32;
      const float4 fa = *reinterpret_cast<const float4*>(&f1k[jglob + kg * 8]);
      const float4 fb = *reinterpret_cast<const float4*>(&f1k[jglob + kg * 8 + 4]);

      short8 bfrag[4];
#pragma unroll
      for (int n = 0; n < 4; n++) {
        const int row_b = n * 16 + col;
        const int u = jq * 8 + ks * 4 + kg;
        const int pu = u ^ col;
        bfrag[n] = *reinterpret_cast<const short8*>(
            SMEM + buf * 32768 + row_b * 512 + pu * 16);
      }

      const unsigned mb0 = (unsigned)(aw0 >> (ks * 32 + kg * 8)) & 0xffu;
      const unsigned mb1 = (unsigned)(aw1 >> (ks * 32 + kg * 8)) & 0xffu;
      const float fv[8] = {fa.x, fa.y, fa.z, fa.w, fb.x, fb.y, fb.z, fb.w};
      short8 af0, af1;
#pragma unroll
      for (int e = 0; e < 8; e++) {
        float s0 = f2r0 + fv[e];
        s0 = fmaxf(s0, NEG_SLOPE * s0);
        float w0 = __expf(s0);
        w0 = (mb0 & (1u << e)) ? w0 : 0.f;
        af0[e] = (short)f2bs(w0);
        float s1 = f2r1 + fv[e];
        s1 = fmaxf(s1, NEG_SLOPE * s1);
        float w1 = __expf(s1);
        w1 = (mb1 & (1u << e)) ? w1 : 0.f;
        af1[e] = (short)f2bs(w1);
      }

      accden[0] = __builtin_amdgcn_mfma_f32_16x16x32_bf16(af0, bones, accden[0], 0, 0, 0);
      accden[1] = __builtin_amdgcn_mfma_f32_16x16x32_bf16(af1, bones, accden[1], 0, 0, 0);
#pragma unroll
      for (int n = 0; n < 4; n++) {
        acc[0][n] = __builtin_amdgcn_mfma_f32_16x16x32_bf16(af0, bfrag[n], acc[0][n], 0, 0, 0);
        acc[1][n] = __builtin_amdgcn_mfma_f32_16x16x32_bf16(af1, bfrag[n], acc[1][n], 0, 0, 0);
      }
    }
  };

  stage(0, 0);
  for (int t = 0; t < NTILE; ++t) {
    const int cur = t & 1;
    __builtin_amdgcn_s_barrier();
    __builtin_amdgcn_sched_barrier(0);
    if (t + 1 < NTILE) {
      stage(t + 1, 1 - cur);
      asm volatile("s_waitcnt vmcnt(4)" ::: "memory");
    } else {
      asm volatile("s_waitcnt vmcnt(0)" ::: "memory");
    }
    __builtin_amdgcn_s_barrier();
    __builtin_amdgcn_sched_barrier(0);
    compute_tile(t, cur);
  }
  __syncthreads();

  float* CL = (float*)SMEM;
  if (jq != 0) {
#pragma unroll
    for (int a = 0; a < 2; a++) {
#pragma unroll
      for (int n = 0; n < 4; n++)
#pragma unroll
        for (int r = 0; r < 4; r++)
          CL[((iq * 3 + (jq - 1)) * 32 + a * 16 + kg * 4 + r) * 64 + n * 16 + col] =
              acc[a][n][r];
      if (col == 0)
#pragma unroll
        for (int r = 0; r < 4; r++) DL[iq][jq][a * 16 + kg * 4 + r] = accden[a][r];
    }
  } else {
#pragma unroll
    for (int a = 0; a < 2; a++)
      if (col == 0)
#pragma unroll
        for (int r = 0; r < 4; r++) DL[iq][0][a * 16 + kg * 4 + r] = accden[a][r];
  }
  __syncthreads();
  if (jq == 0) {
#pragma unroll
    for (int a = 0; a < 2; a++) {
#pragma unroll
      for (int r = 0; r < 4; r++) {
        const int il = a * 16 + kg * 4 + r;
        const float den = DL[iq][0][il] + DL[iq][1][il] + DL[iq][2][il] + DL[iq][3][il];
        const float rinv = 1.f / den;
#pragma unroll
        for (int n = 0; n < 4; n++) {
          float v = acc[a][n][r];
          v += CL[((iq * 3 + 0) * 32 + il) * 64 + n * 16 + col];
          v += CL[((iq * 3 + 1) * 32 + il) * 64 + n * 16 + col];
          v += CL[((iq * 3 + 2) * 32 + il) * 64 + n * 16 + col];
          out[(size_t)(i0 + iq * 32 + il) * KFP + k * 64 + n * 16 + col] = v * rinv;
        }
      }
    }
  }
}

// ---------------- launch ----------------------------------------------------------------
extern "C" void kernel_launch(void* const* d_in, const int* in_sizes, int n_in,
                              void* d_out, int out_size, void* d_ws, size_t ws_size,
                              hipStream_t stream) {
  const float* X   = (const float*)d_in[0];             // (N, F)
  const int*   adj = (const int*)d_in[1];               // (N, N)
  const float* W   = (const float*)d_in[2];             // (K, F, FP)
  const float* a   = (const float*)d_in[3];             // (K, 2*FP, 1)
  float* out = (float*)d_out;                           // (N, K*FP) = 8 MB

  char* ws = (char*)d_ws;
  unsigned short* h_bT = (unsigned short*)(ws);                    // 4 MB
  float* f1  = (float*)(ws + 4194304);                             // 128 KB
  float* f2  = (float*)(ws + 4325376);                             // 128 KB
  unsigned long long* adjb = (unsigned long long*)(ws + 4456448);  // 2 MB
  unsigned short* Wt = (unsigned short*)(ws + 6553600);            // 512 KB
  // Xb parked in d_out (4 MB of its 8 MB) — consumed by gemm_h before attn overwrites out
  unsigned short* Xb = (unsigned short*)d_out;

  const int nwords = N * (N / 64);
  hipLaunchKernelGGL(adj_to_bits, dim3(1024), dim3(256), 0, stream, adj, adjb, nwords);
  hipLaunchKernelGGL(xb_prep, dim3(N * F / (256 * 8)), dim3(256), 0, stream, X, Xb);
  hipLaunchKernelGGL(wt_prep, dim3(K * (F / 64)), dim3(256), 0, stream, W, Wt);
  hipLaunchKernelGGL(gemm_h, dim3(K * (N / 64)), dim3(256), 0, stream,
                     Xb, Wt, a, h_bT, f1, f2);
  hipLaunchKernelGGL(attn_mfma, dim3((N / BI) * K), dim3(512), 0, stream,
                     h_bT, f1, f2, adjb, out);
}

// Round 5
// 85.971 us; speedup vs baseline: 5.5422x; 1.2413x over previous
//
#include <hip/hip_runtime.h>

#define N 4096
#define F 512
#define FP 64
#define K 8
#define KFP 512          // K*FP
#define LOG2E 1.44269504088896f

#define BI 64            // attn: i-rows per block
#define BJ 256           // attn: j-cols staged per tile
#define NTILE (N / BJ)   // 16

typedef __attribute__((ext_vector_type(8))) short short8;
typedef __attribute__((ext_vector_type(4))) float f32x4;

__device__ __forceinline__ unsigned short f2bs(float x) {
  union { __bf16 b; unsigned short u; } u;
  u.b = (__bf16)x;
  return u.u;
}

#if __has_builtin(__builtin_amdgcn_exp2f)
#define EXP2(x) __builtin_amdgcn_exp2f(x)
#else
#define EXP2(x) __expf((x) * 0.6931471805599453f)
#endif

__device__ __forceinline__ int sext_bit(unsigned v, int off) {
#if __has_builtin(__builtin_amdgcn_sbfe)
  return __builtin_amdgcn_sbfe((int)v, off, 1);     // 0 or -1
#else
  return ((int)(v << (31 - off))) >> 31;
#endif
}

// masked = bit(off) of mb ? w : 0.0f   (2 VALU: sbfe + and)
__device__ __forceinline__ float mask_w(float w, unsigned mb, int off) {
  return __int_as_float(__float_as_int(w) & sext_bit(mb, off));
}

// ---------------- prep: Xb = bf16(X), Wt = bf16(W transposed) ----------------------------
__global__ __launch_bounds__(256) void prep_fused(const float* __restrict__ X,
                                                  unsigned short* __restrict__ Xb,
                                                  const float* __restrict__ W,
                                                  unsigned short* __restrict__ Wt) {
  __shared__ unsigned short WT16[64][66];
  const int t = threadIdx.x;
  if (blockIdx.x < 1024) {                  // X -> Xb, 8 elems/thread
    const int idx = (blockIdx.x * 256 + t) * 8;
    const float4 v0 = *reinterpret_cast<const float4*>(&X[idx]);
    const float4 v1 = *reinterpret_cast<const float4*>(&X[idx + 4]);
    unsigned short o[8] = {f2bs(v0.x), f2bs(v0.y), f2bs(v0.z), f2bs(v0.w),
                           f2bs(v1.x), f2bs(v1.y), f2bs(v1.z), f2bs(v1.w)};
    *reinterpret_cast<uint4*>(&Xb[idx]) = *reinterpret_cast<uint4*>(&o[0]);
    return;
  }
  const int bid = blockIdx.x - 1024;        // W[K][F][FP] -> Wt[K*FP][F]
  const int k = bid >> 3;
  const int f0 = (bid & 7) * 64;
#pragma unroll
  for (int j = 0; j < 16; j++) {
    const int idx = j * 256 + t;
    const int fl = idx >> 6, p = idx & 63;
    WT16[p][fl] = f2bs(W[(k * F + f0 + fl) * FP + p]);
  }
  __syncthreads();
  const int p = t >> 2, uc = t & 3;
  unsigned short tmp[16];
#pragma unroll
  for (int j = 0; j < 16; j++) tmp[j] = WT16[p][uc * 16 + j];
  unsigned short* dst = &Wt[(k * 64 + p) * F + f0 + uc * 16];
  *reinterpret_cast<uint4*>(dst)     = *reinterpret_cast<uint4*>(&tmp[0]);
  *reinterpret_cast<uint4*>(dst + 8) = *reinterpret_cast<uint4*>(&tmp[8]);
}

// ---------------- kernel A: h_bT = Wt·Xb^T via MFMA + fused f1/f2 + fused adj bits -------
// block = (head k, 64-node tile). 4 waves. Adjacency bit conversion rides the pipeline.
__global__ __launch_bounds__(256, 2) void gemm_h(
    const unsigned short* __restrict__ Xb, const unsigned short* __restrict__ Wt,
    const float* __restrict__ a, unsigned short* __restrict__ h_bT,
    float* __restrict__ f1, float* __restrict__ f2,
    const int* __restrict__ adj, unsigned long long* __restrict__ adjb) {
  __shared__ __align__(16) unsigned char AT[2][8192];   // Wt tile [64c][8u][16B]
  __shared__ __align__(16) unsigned char BT[2][8192];   // Xb tile [64n][8u][16B]
  __shared__ float F1L[2][64], F2L[2][64];

  const int t = threadIdx.x;
  const int k = blockIdx.x & 7;
  const int n0 = (blockIdx.x >> 3) * 64;
  const int wave = t >> 6, lane = t & 63;
  const int cg = wave >> 1, ng = wave & 1;
  const int col = lane & 15, kg = lane >> 4;
  const unsigned short* __restrict__ Wk = Wt + (size_t)k * 64 * F;

  f32x4 acc[2][2];
#pragma unroll
  for (int i = 0; i < 2; i++)
#pragma unroll
    for (int j = 0; j < 2; j++) acc[i][j] = (f32x4){0.f, 0.f, 0.f, 0.f};

  auto stage = [&](int tt, int buf) {
    const int f0 = tt * 64;
#pragma unroll
    for (int m = 0; m < 2; m++) {
      const int g = wave * 128 + m * 64 + lane;
      const int row = g >> 3, pu = g & 7;
      const int u = pu ^ (row & 7);
      const void* srcA = Wk + (size_t)row * F + f0 + u * 8;
      void* dstA = (void*)(AT[buf] + (wave * 128 + m * 64) * 16);
      __builtin_amdgcn_global_load_lds(
          (const __attribute__((address_space(1))) void*)srcA,
          (__attribute__((address_space(3))) void*)dstA, 16, 0, 0);
      const void* srcB = Xb + (size_t)(n0 + row) * F + f0 + u * 8;
      void* dstB = (void*)(BT[buf] + (wave * 128 + m * 64) * 16);
      __builtin_amdgcn_global_load_lds(
          (const __attribute__((address_space(1))) void*)srcB,
          (__attribute__((address_space(3))) void*)dstB, 16, 0, 0);
    }
  };

  auto compute = [&](int buf) {
#pragma unroll
    for (int ks = 0; ks < 2; ks++) {
      const int u0 = ks * 4 + kg;
      short8 af[2], bf[2];
#pragma unroll
      for (int i = 0; i < 2; i++) {
        const int rowA = cg * 32 + i * 16 + col;
        af[i] = *reinterpret_cast<const short8*>(
            AT[buf] + (rowA * 8 + (u0 ^ (rowA & 7))) * 16);
        const int rowB = ng * 32 + i * 16 + col;
        bf[i] = *reinterpret_cast<const short8*>(
            BT[buf] + (rowB * 8 + (u0 ^ (rowB & 7))) * 16);
      }
#pragma unroll
      for (int i = 0; i < 2; i++)
#pragma unroll
        for (int j = 0; j < 2; j++)
          acc[i][j] = __builtin_amdgcn_mfma_f32_16x16x32_bf16(af[i], bf[j], acc[i][j], 0, 0, 0);
    }
  };

  // fused adjacency: block owns 512 adjb words; wave owns 128; 16 per K-tile.
  int adjv[16];
  const int wb_wave = blockIdx.x * 512 + wave * 128;
  auto adj_load = [&](int c) {
    const int* p = adj + (size_t)(wb_wave + c * 16) * 64 + lane;
#pragma unroll
    for (int x = 0; x < 16; x++) adjv[x] = p[x * 64];
  };
  auto adj_process = [&](int c) {
    unsigned long long ms[16];
#pragma unroll
    for (int x = 0; x < 16; x++) ms[x] = __ballot(adjv[x] > 0);
    if (lane == 0) {
#pragma unroll
      for (int x = 0; x < 16; x++) adjb[wb_wave + c * 16 + x] = ms[x];
    }
  };

  stage(0, 0);
  adj_load(0);
  for (int tt = 0; tt < F / 64; ++tt) {
    const int cur = tt & 1;
    __builtin_amdgcn_s_barrier();
    __builtin_amdgcn_sched_barrier(0);
    if (tt + 1 < F / 64) {
      stage(tt + 1, 1 - cur);
      asm volatile("s_waitcnt vmcnt(4)" ::: "memory");   // retires stage(tt) AND adj chunk tt-1
    } else {
      asm volatile("s_waitcnt vmcnt(0)" ::: "memory");
    }
    __builtin_amdgcn_s_barrier();
    __builtin_amdgcn_sched_barrier(0);
    if (tt >= 1) {
      adj_process(tt - 1);
      adj_load(tt);
    }
    compute(cur);
  }
  asm volatile("s_waitcnt vmcnt(0)" ::: "memory");
  adj_process(7);

  // ---- epilogue: h_bT bf16 stores + fused f1/f2 (pre-scaled by log2e) ----
  float p1[2] = {0.f, 0.f}, p2[2] = {0.f, 0.f};
#pragma unroll
  for (int i = 0; i < 2; i++) {
#pragma unroll
    for (int r = 0; r < 4; r++) {
      const int p = cg * 32 + i * 16 + kg * 4 + r;
      const float as = a[k * 128 + p];
      const float ad = a[k * 128 + 64 + p];
#pragma unroll
      for (int j = 0; j < 2; j++) {
        const float v = acc[i][j][r];
        h_bT[(size_t)(k * 64 + p) * N + n0 + ng * 32 + j * 16 + col] = f2bs(v);
        p1[j] = fmaf(v, as, p1[j]);
        p2[j] = fmaf(v, ad, p2[j]);
      }
    }
  }
#pragma unroll
  for (int j = 0; j < 2; j++) {
    p1[j] += __shfl_xor(p1[j], 16); p1[j] += __shfl_xor(p1[j], 32);
    p2[j] += __shfl_xor(p2[j], 16); p2[j] += __shfl_xor(p2[j], 32);
    if (kg == 0) {
      F1L[cg][ng * 32 + j * 16 + col] = p1[j];
      F2L[cg][ng * 32 + j * 16 + col] = p2[j];
    }
  }
  __syncthreads();
  if (t < 64) {
    f1[k * N + n0 + t] = (F1L[0][t] + F1L[1][t]) * LOG2E;
    f2[k * N + n0 + t] = (F2L[0][t] + F2L[1][t]) * LOG2E;
  }
}

// ---------------- kernel C: LDS-staged MFMA masked-softmax attention ---------------------
__global__ __launch_bounds__(512, 4) void attn_mfma(
    const unsigned short* __restrict__ h_bT, const float* __restrict__ f1,
    const float* __restrict__ f2, const unsigned long long* __restrict__ adjb,
    float* __restrict__ out) {
  __shared__ __align__(16) unsigned char SMEM[65536];
  __shared__ float DL[2][4][32];

  const int tid = threadIdx.x;
  const int k = blockIdx.x & 7;
  const int i0 = (blockIdx.x >> 3) * BI;
  const int wave = tid >> 6, lane = tid & 63;
  const int iq = wave >> 2;
  const int jq = wave & 3;
  const int col = lane & 15, kg = lane >> 4;

  const float* __restrict__ f1k = f1 + k * N;
  const unsigned char* __restrict__ hbb =
      (const unsigned char*)(h_bT + (size_t)k * 64 * N);

  const int rbase = i0 + iq * 32;
  const float f2r0 = f2[k * N + rbase + col];        // pre-scaled by log2e
  const float f2r1 = f2[k * N + rbase + 16 + col];
  const unsigned long long* __restrict__ arow0 = adjb + (size_t)(rbase + col) * 64;
  const unsigned long long* __restrict__ arow1 = adjb + (size_t)(rbase + 16 + col) * 64;

  f32x4 acc[2][4];
  f32x4 accden[2];
#pragma unroll
  for (int a = 0; a < 2; a++) {
    accden[a] = (f32x4){0.f, 0.f, 0.f, 0.f};
#pragma unroll
    for (int n = 0; n < 4; n++) acc[a][n] = (f32x4){0.f, 0.f, 0.f, 0.f};
  }
  short8 bones;
#pragma unroll
  for (int e = 0; e < 8; e++) bones[e] = (short)0x3F80;

  auto stage = [&](int tt, int buf) {
#pragma unroll
    for (int m = 0; m < 4; m++) {
      const int g = wave * 4 + m;
      const int row = g * 2 + (lane >> 5);
      const int pu = lane & 31;
      const int u = pu ^ (row & 15);
      const void* src = hbb + (size_t)row * (N * 2) + tt * (BJ * 2) + u * 16;
      void* dst = (void*)(SMEM + buf * 32768 + g * 1024);
      __builtin_amdgcn_global_load_lds(
          (const __attribute__((address_space(1))) void*)src,
          (__attribute__((address_space(3))) void*)dst, 16, 0, 0);
    }
  };

  auto compute_tile = [&](int tt, int buf) {
    const uint2 aw0 = *reinterpret_cast<const uint2*>(arow0 + tt * 4 + jq);
    const uint2 aw1 = *reinterpret_cast<const uint2*>(arow1 + tt * 4 + jq);
#pragma unroll
    for (int ks = 0; ks < 2; ks++) {
      const int jglob = tt * BJ + jq * 64 + ks * 32;
      const float4 fa = *reinterpret_cast<const float4*>(&f1k[jglob + kg * 8]);
      const float4 fb = *reinterpret_cast<const float4*>(&f1k[jglob + kg * 8 + 4]);

      short8 bfrag[4];
#pragma unroll
      for (int n = 0; n < 4; n++) {
        const int row_b = n * 16 + col;
        const int u = jq * 8 + ks * 4 + kg;
        const int pu = u ^ col;
        bfrag[n] = *reinterpret_cast<const short8*>(
            SMEM + buf * 32768 + row_b * 512 + pu * 16);
      }

      const unsigned mb0 = (ks ? aw0.y : aw0.x) >> (kg * 8);
      const unsigned mb1 = (ks ? aw1.y : aw1.x) >> (kg * 8);
      const float fv[8] = {fa.x, fa.y, fa.z, fa.w, fb.x, fb.y, fb.z, fb.w};

      union { unsigned u[4]; short8 s; } A0, A1;
#pragma unroll
      for (int e2 = 0; e2 < 4; e2++) {
        const float va = fv[2 * e2], vb = fv[2 * e2 + 1];
        float t0a = f2r0 + va, t0b = f2r0 + vb;
        float t1a = f2r1 + va, t1b = f2r1 + vb;
        t0a = fmaxf(t0a, 0.2f * t0a); t0b = fmaxf(t0b, 0.2f * t0b);
        t1a = fmaxf(t1a, 0.2f * t1a); t1b = fmaxf(t1b, 0.2f * t1b);
        float w0a = EXP2(t0a), w0b = EXP2(t0b);
        float w1a = EXP2(t1a), w1b = EXP2(t1b);
        w0a = mask_w(w0a, mb0, 2 * e2); w0b = mask_w(w0b, mb0, 2 * e2 + 1);
        w1a = mask_w(w1a, mb1, 2 * e2); w1b = mask_w(w1b, mb1, 2 * e2 + 1);
        asm("v_cvt_pk_bf16_f32 %0, %1, %2" : "=v"(A0.u[e2]) : "v"(w0a), "v"(w0b));
        asm("v_cvt_pk_bf16_f32 %0, %1, %2" : "=v"(A1.u[e2]) : "v"(w1a), "v"(w1b));
      }

      accden[0] = __builtin_amdgcn_mfma_f32_16x16x32_bf16(A0.s, bones, accden[0], 0, 0, 0);
      accden[1] = __builtin_amdgcn_mfma_f32_16x16x32_bf16(A1.s, bones, accden[1], 0, 0, 0);
#pragma unroll
      for (int n = 0; n < 4; n++) {
        acc[0][n] = __builtin_amdgcn_mfma_f32_16x16x32_bf16(A0.s, bfrag[n], acc[0][n], 0, 0, 0);
        acc[1][n] = __builtin_amdgcn_mfma_f32_16x16x32_bf16(A1.s, bfrag[n], acc[1][n], 0, 0, 0);
      }
    }
  };

  stage(0, 0);
  for (int t = 0; t < NTILE; ++t) {
    const int cur = t & 1;
    __builtin_amdgcn_s_barrier();
    __builtin_amdgcn_sched_barrier(0);
    if (t + 1 < NTILE) {
      stage(t + 1, 1 - cur);
      asm volatile("s_waitcnt vmcnt(4)" ::: "memory");
    } else {
      asm volatile("s_waitcnt vmcnt(0)" ::: "memory");
    }
    __builtin_amdgcn_s_barrier();
    __builtin_amdgcn_sched_barrier(0);
    compute_tile(t, cur);
  }
  __syncthreads();

  // ---- cross-jq reduction (CL aliases SMEM, stride 66 to dodge bank conflicts) ----
  float* CL = (float*)SMEM;
  if (jq != 0) {
#pragma unroll
    for (int a = 0; a < 2; a++) {
#pragma unroll
      for (int n = 0; n < 4; n++)
#pragma unroll
        for (int r = 0; r < 4; r++)
          CL[((iq * 3 + (jq - 1)) * 32 + a * 16 + kg * 4 + r) * 66 + n * 16 + col] =
              acc[a][n][r];
      if (col == 0)
#pragma unroll
        for (int r = 0; r < 4; r++) DL[iq][jq][a * 16 + kg * 4 + r] = accden[a][r];
    }
  } else {
#pragma unroll
    for (int a = 0; a < 2; a++)
      if (col == 0)
#pragma unroll
        for (int r = 0; r < 4; r++) DL[iq][0][a * 16 + kg * 4 + r] = accden[a][r];
  }
  __syncthreads();
  if (jq == 0) {
#pragma unroll
    for (int a = 0; a < 2; a++) {
#pragma unroll
      for (int r = 0; r < 4; r++) {
        const int il = a * 16 + kg * 4 + r;
        const float den = DL[iq][0][il] + DL[iq][1][il] + DL[iq][2][il] + DL[iq][3][il];
        const float rinv = 1.f / den;
#pragma unroll
        for (int n = 0; n < 4; n++) {
          float v = acc[a][n][r];
          v += CL[((iq * 3 + 0) * 32 + il) * 66 + n * 16 + col];
          v += CL[((iq * 3 + 1) * 32 + il) * 66 + n * 16 + col];
          v += CL[((iq * 3 + 2) * 32 + il) * 66 + n * 16 + col];
          out[(size_t)(i0 + iq * 32 + il) * KFP + k * 64 + n * 16 + col] = v * rinv;
        }
      }
    }
  }
}

// ---------------- launch ----------------------------------------------------------------
extern "C" void kernel_launch(void* const* d_in, const int* in_sizes, int n_in,
                              void* d_out, int out_size, void* d_ws, size_t ws_size,
                              hipStream_t stream) {
  const float* X   = (const float*)d_in[0];             // (N, F)
  const int*   adj = (const int*)d_in[1];               // (N, N)
  const float* W   = (const float*)d_in[2];             // (K, F, FP)
  const float* a   = (const float*)d_in[3];             // (K, 2*FP, 1)
  float* out = (float*)d_out;                           // (N, K*FP) = 8 MB

  char* ws = (char*)d_ws;
  unsigned short* h_bT = (unsigned short*)(ws);                    // 4 MB
  float* f1  = (float*)(ws + 4194304);                             // 128 KB
  float* f2  = (float*)(ws + 4325376);                             // 128 KB
  unsigned long long* adjb = (unsigned long long*)(ws + 4456448);  // 2 MB
  unsigned short* Wt = (unsigned short*)(ws + 6553600);            // 512 KB
  // Xb parked in d_out (4 MB of its 8 MB) — consumed by gemm_h before attn overwrites out
  unsigned short* Xb = (unsigned short*)d_out;

  hipLaunchKernelGGL(prep_fused, dim3(1024 + K * (F / 64)), dim3(256), 0, stream,
                     X, Xb, W, Wt);
  hipLaunchKernelGGL(gemm_h, dim3(K * (N / 64)), dim3(256), 0, stream,
                     Xb, Wt, a, h_bT, f1, f2, adj, adjb);
  hipLaunchKernelGGL(attn_mfma, dim3((N / BI) * K), dim3(512), 0, stream,
                     h_bT, f1, f2, adjb, out);
}